// Round 1
// baseline (159.782 us; speedup 1.0000x reference)
//
#include <hip/hip_runtime.h>
#include <cstdint>
#include <cstddef>

// Problem constants (fixed by the reference: N=4096, D=512)
constexpr int N_ROWS = 4096;
constexpr int D      = 512;
constexpr int M      = 8192;   // 2N

using f32x4  = __attribute__((ext_vector_type(4))) float;
using bf16x8 = __attribute__((ext_vector_type(8))) __bf16;
using us8    = __attribute__((ext_vector_type(8))) unsigned short;

// RNE float -> bf16 (inputs are finite, no NaN handling needed)
__device__ inline unsigned short f2bf(float f) {
    unsigned int u = __float_as_uint(f);
    u += 0x7fffu + ((u >> 16) & 1u);
    return (unsigned short)(u >> 16);
}
__device__ inline float bf2f(unsigned short s) {
    return __uint_as_float(((unsigned int)s) << 16);
}

// 16B async global->LDS copy. LDS dest must be wave-uniform base; HW writes
// lane l at base + l*16.
#define ASYNC_CP16(gsrc, ldst)                                                      \
    __builtin_amdgcn_global_load_lds(                                               \
        (const __attribute__((address_space(1))) unsigned int*)(gsrc),              \
        (__attribute__((address_space(3))) unsigned int*)(ldst), 16, 0, 0)

// ---------------------------------------------------------------------------
// Kernel 1: row L2-normalize -> bf16 Z in ws; also inv_norm, diag sumsq of the
// bf16-rounded row (matches what the MFMA diagonal will compute), and zero
// rowsum (ws is poisoned 0xAA before every timed launch).
// One wave per row: 64 lanes x 8 floats = 512.
// ---------------------------------------------------------------------------
__global__ __launch_bounds__(256) void normalize_kernel(
    const float* __restrict__ emb_i, const float* __restrict__ emb_j,
    unsigned short* __restrict__ zb, float* __restrict__ rowsum,
    float* __restrict__ diagss, float* __restrict__ invn)
{
    const int wave = threadIdx.x >> 6, lane = threadIdx.x & 63;
    const int row = blockIdx.x * 4 + wave;
    const float* __restrict__ src = (row < N_ROWS)
        ? (emb_i + (size_t)row * D)
        : (emb_j + (size_t)(row - N_ROWS) * D);
    float4 v0 = ((const float4*)src)[lane * 2];
    float4 v1 = ((const float4*)src)[lane * 2 + 1];
    float ss = v0.x*v0.x + v0.y*v0.y + v0.z*v0.z + v0.w*v0.w
             + v1.x*v1.x + v1.y*v1.y + v1.z*v1.z + v1.w*v1.w;
    #pragma unroll
    for (int off = 32; off; off >>= 1) ss += __shfl_xor(ss, off, 64);
    const float inv = rsqrtf(ss);
    const float z[8] = {v0.x*inv, v0.y*inv, v0.z*inv, v0.w*inv,
                        v1.x*inv, v1.y*inv, v1.z*inv, v1.w*inv};
    us8 p;
    float dss = 0.f;
    #pragma unroll
    for (int j = 0; j < 8; ++j) {
        unsigned short b = f2bf(z[j]);
        p[j] = b;
        float f = bf2f(b);
        dss += f * f;
    }
    *(us8*)(zb + (size_t)row * D + lane * 8) = p;
    #pragma unroll
    for (int off = 32; off; off >>= 1) dss += __shfl_xor(dss, off, 64);
    if (lane == 0) {
        rowsum[row] = 0.0f;
        diagss[row] = dss;
        invn[row]   = inv;
    }
}

// ---------------------------------------------------------------------------
// Kernel 2: fused sim = Z·Z^T (bf16 MFMA), exp(2*sim), row-sum -> atomicAdd.
// 128x128 tile per block, 4 waves in 2x2 (64x64 each), BK=32,
// mfma_f32_16x16x32_bf16, 16B global_load_lds staging.
// LDS tile layout [128][32] bf16 with XOR chunk swizzle: phys 16B-chunk
// p = logical_c ^ ((row>>1)&3)  -> ds_read_b128 lands 2-way on banks (free).
// ---------------------------------------------------------------------------
__global__ __launch_bounds__(256, 3) void simgemm_kernel(
    const unsigned short* __restrict__ zb, float* __restrict__ rowsum)
{
    __shared__ unsigned short As[128 * 32];
    __shared__ unsigned short Bs[128 * 32];
    const int tid  = threadIdx.x;
    const int wave = tid >> 6, lane = tid & 63;
    const int l15  = lane & 15, ks = lane >> 4;
    const int bx = blockIdx.x, by = blockIdx.y;
    const int wrow = (wave >> 1) * 64, wcol = (wave & 1) * 64;

    // Staging mapping: tile = 8 chunks of 1024B (16 rows each); wave w owns
    // chunks {2w, 2w+1}. lane l -> row chunk*16 + (l>>2), phys 16B slot l&3.
    const int ch0 = wave * 2;
    const int sr0 = ch0 * 16 + (lane >> 2);
    const int sc  = ((lane & 3) ^ ((sr0 >> 1) & 3)) * 8;   // swizzled k-offset (elems)
    const unsigned short* gA0 = zb + (size_t)(bx * 128 + sr0) * D + sc;
    const unsigned short* gB0 = zb + (size_t)(by * 128 + sr0) * D + sc;
    unsigned short* lA0 = As + ch0 * 512;
    unsigned short* lA1 = As + ch0 * 512 + 512;
    unsigned short* lB0 = Bs + ch0 * 512;
    unsigned short* lB1 = Bs + ch0 * 512 + 512;

    f32x4 acc[4][4] = {};
    const int swOff = (ks ^ ((l15 >> 1) & 3)) * 8;  // swizzled frag k-offset (elems)

    for (int kc = 0; kc < D; kc += 32) {
        ASYNC_CP16(gA0 + kc,          lA0);
        ASYNC_CP16(gA0 + kc + 16 * D, lA1);
        ASYNC_CP16(gB0 + kc,          lB0);
        ASYNC_CP16(gB0 + kc + 16 * D, lB1);
        __syncthreads();

        bf16x8 af[4], bg[4];
        #pragma unroll
        for (int f = 0; f < 4; ++f) {
            af[f] = *(const bf16x8*)(As + (wrow + f * 16 + l15) * 32 + swOff);
            bg[f] = *(const bf16x8*)(Bs + (wcol + f * 16 + l15) * 32 + swOff);
        }
        #pragma unroll
        for (int i = 0; i < 4; ++i)
            #pragma unroll
            for (int j = 0; j < 4; ++j)
                acc[i][j] = __builtin_amdgcn_mfma_f32_16x16x32_bf16(
                    af[i], bg[j], acc[i][j], 0, 0, 0);
        __syncthreads();
    }

    // Epilogue: e = exp(sim/T) = exp(2*acc); C/D layout: row=(lane>>4)*4+r,
    // col=lane&15. Reduce across the 16 col-lanes, atomicAdd per row.
    float* rs = rowsum + bx * 128 + wrow;
    #pragma unroll
    for (int i = 0; i < 4; ++i) {
        #pragma unroll
        for (int r = 0; r < 4; ++r) {
            float e = __expf(2.0f * acc[i][0][r]) + __expf(2.0f * acc[i][1][r])
                    + __expf(2.0f * acc[i][2][r]) + __expf(2.0f * acc[i][3][r]);
            e += __shfl_xor(e, 1, 64);
            e += __shfl_xor(e, 2, 64);
            e += __shfl_xor(e, 4, 64);
            e += __shfl_xor(e, 8, 64);
            if (l15 == 0) atomicAdd(rs + i * 16 + ks * 4 + r, e);
        }
    }
}

// ---------------------------------------------------------------------------
// Kernel 3: positive-pair logits, fp32 exact path:
// pos[k] = 2 * dot(emb_i[k], emb_j[k]) * inv[k] * inv[k+N]
// ---------------------------------------------------------------------------
__global__ __launch_bounds__(256) void pos_kernel(
    const float* __restrict__ emb_i, const float* __restrict__ emb_j,
    const float* __restrict__ invn, float* __restrict__ pos)
{
    const int wave = threadIdx.x >> 6, lane = threadIdx.x & 63;
    const int k = blockIdx.x * 4 + wave;
    const float4* a = (const float4*)(emb_i + (size_t)k * D);
    const float4* b = (const float4*)(emb_j + (size_t)k * D);
    float4 a0 = a[lane * 2], a1 = a[lane * 2 + 1];
    float4 b0 = b[lane * 2], b1 = b[lane * 2 + 1];
    float d = a0.x*b0.x + a0.y*b0.y + a0.z*b0.z + a0.w*b0.w
            + a1.x*b1.x + a1.y*b1.y + a1.z*b1.z + a1.w*b1.w;
    #pragma unroll
    for (int off = 32; off; off >>= 1) d += __shfl_xor(d, off, 64);
    if (lane == 0) pos[k] = 2.0f * d * invn[k] * invn[k + N_ROWS];
}

// ---------------------------------------------------------------------------
// Kernel 4: loss = [ sum_i log(rowsum_i - exp(2*diagss_i)) - 2*sum_k pos_k ] / 8192
// ---------------------------------------------------------------------------
__global__ __launch_bounds__(1024) void finalize_kernel(
    const float* __restrict__ rowsum, const float* __restrict__ diagss,
    const float* __restrict__ pos, float* __restrict__ out)
{
    float local = 0.f;
    for (int i = threadIdx.x; i < M; i += 1024)
        local += __logf(rowsum[i] - __expf(2.0f * diagss[i]));
    for (int k = threadIdx.x; k < N_ROWS; k += 1024)
        local -= 2.0f * pos[k];
    #pragma unroll
    for (int off = 32; off; off >>= 1) local += __shfl_xor(local, off, 64);
    __shared__ float red[16];
    const int wave = threadIdx.x >> 6, lane = threadIdx.x & 63;
    if (lane == 0) red[wave] = local;
    __syncthreads();
    if (threadIdx.x == 0) {
        float t = 0.f;
        #pragma unroll
        for (int w = 0; w < 16; ++w) t += red[w];
        out[0] = t * (1.0f / 8192.0f);
    }
}

// ---------------------------------------------------------------------------
extern "C" void kernel_launch(void* const* d_in, const int* in_sizes, int n_in,
                              void* d_out, int out_size, void* d_ws, size_t ws_size,
                              hipStream_t stream)
{
    const float* emb_i = (const float*)d_in[0];
    const float* emb_j = (const float*)d_in[1];

    // ws layout: zb bf16 [M][D] (8 MB) | rowsum f32[M] | diagss f32[M]
    //            | invn f32[M] | pos f32[N]   (~8.4 MB total)
    unsigned short* zb = (unsigned short*)d_ws;
    float* rowsum = (float*)((char*)d_ws + (size_t)M * D * sizeof(unsigned short));
    float* diagss = rowsum + M;
    float* invn   = diagss + M;
    float* pos    = invn + M;
    float* out    = (float*)d_out;

    normalize_kernel<<<M / 4, 256, 0, stream>>>(emb_i, emb_j, zb, rowsum, diagss, invn);
    simgemm_kernel<<<dim3(M / 128, M / 128), 256, 0, stream>>>(zb, rowsum);
    pos_kernel<<<N_ROWS / 4, 256, 0, stream>>>(emb_i, emb_j, invn, pos);
    finalize_kernel<<<1, 1024, 0, stream>>>(rowsum, diagss, pos, out);
}